// Round 5
// baseline (2477.999 us; speedup 1.0000x reference)
//
#include <hip/hip_runtime.h>
#include <hip/hip_fp16.h>
#include <stdint.h>

#define RES 8192
#define TSTEPS 512
#define CAP 960                          // mean nnz 819, sigma 27 -> +5.2 sigma headroom
#define NB 256
#define NT 512
#define ROWS_PER_BLOCK 32
#define LPR 16                           // lanes per row
#define PW_ITERS (CAP / LPR / 4)         // 15 uint4 per lane, register-resident
#define NGROUP 8
#define GSTRIDE 16                       // dwords between group counters (64 B -> distinct lines)

// workspace layout (bytes)
#define WS_PACKED_OFF   0u
#define WS_H16_OFF      31457280u                    // 8192*960*4
#define WS_FLAGS_OFF    (31457280u + 8404992u)       // + 513*4096*4 = 39862272

// Compress W row -> packed (col<<19 | f32-rounded-to-19bit), with per-lane
// bank-ring ordering: gather-wave lane (row&1)*16+li starts its slot sequence
// at bank rot and walks the bank ring, so every unrolled gather instruction
// sees each LDS bank loaded ~2x (2-way = free).
__global__ __launch_bounds__(256) void esn_compress(const float* __restrict__ W,
                                                    uint32_t* __restrict__ packed) {
    __shared__ uint32_t lst[4][CAP];
    const int wave = threadIdx.x >> 6;
    const int lane = threadIdx.x & 63;
    const int row  = blockIdx.x * 4 + wave;
    const float* wrow = W + (size_t)row * RES;
    uint32_t* prow = packed + (size_t)row * CAP;
    unsigned nnz = 0;
    for (int chunk = 0; chunk < RES / 64; ++chunk) {
        const int c = chunk * 64 + lane;
        const float v = wrow[c];
        const bool nz = (v != 0.0f);
        const unsigned long long m = __ballot(nz);
        if (nz) {
            unsigned pos = nnz + (unsigned)__popcll(m & ((1ull << lane) - 1ull));
            if (pos < CAP) {
                uint32_t b = __float_as_uint(v) + 0x1000u;   // round-to-nearest at 19-bit cut
                lst[wave][pos] = ((uint32_t)c << 19) | (b >> 13);
            }
        }
        nnz += (unsigned)__popcll(m);
    }
    if (nnz > CAP) nnz = CAP;
    for (unsigned s = nnz + (unsigned)lane; s < CAP; s += 64) lst[wave][s] = 0u;  // pad: col 0, val +0.0
    __syncthreads();

    // per-lane bank-ring grouping (deterministic; one-time cost)
    if (lane < 16) {
        const int li = lane;
        const unsigned rot = ((unsigned)(row & 1) << 4) | (unsigned)li;
        int p = 0;
        for (unsigned bp = 0; bp < 32; ++bp) {
            const unsigned want = (rot + bp) & 31u;
            for (int k = 0; k < CAP / 16; ++k) {
                const uint32_t e = lst[wave][k * 16 + li];
                const unsigned bank = (e >> 19) & 31u;       // col & 31
                if (bank == want) {
                    // lane's p-th slot -> dword (p/4)*64 + li*4 + (p%4)  (= uint4 i*16+li, comp p%4)
                    prow[(p >> 2) * 64 + (li << 2) + (p & 3)] = e;
                    ++p;
                }
            }
        }
    }
}

__device__ __forceinline__ float2 unpack_h2(unsigned u) {
    __half2 h = *reinterpret_cast<__half2*>(&u);
    return __half22float2(h);
}

__global__ __launch_bounds__(NT) void esn_loop(const float* __restrict__ x,
                                               const float* __restrict__ Win,
                                               const float* __restrict__ Wout_w,
                                               const float* __restrict__ Wout_b,
                                               const uint32_t* __restrict__ packed,
                                               uint32_t* __restrict__ h16,
                                               unsigned* __restrict__ flags,
                                               float* __restrict__ out) {
    __shared__ float lds_h[RES];
    __shared__ float lds_hnew[ROWS_PER_BLOCK];
    __shared__ float lds_red[NT / 64][3];
    __shared__ float lds_x[TSTEPS * 3];

    const int tid = threadIdx.x;
    const int bid = blockIdx.x;
    const int li  = tid & (LPR - 1);
    const int rlocal = tid >> 4;
    const int row = bid * ROWS_PER_BLOCK + rlocal;
    const bool leader = (li == 0);
    const int grp = bid & (NGROUP - 1);

    // cross-replay cache hygiene: invalidate stale clean lines once
    __builtin_amdgcn_fence(__ATOMIC_ACQUIRE, "agent");

    // stage x into LDS once
    for (int i = tid; i < TSTEPS * 3; i += NT) lds_x[i] = x[i];

    // W row slice into registers: 15 x uint4 = 60 VGPRs
    uint4 pw[PW_ITERS];
    {
        const uint4* prow = ((const uint4*)packed) + (size_t)row * (CAP / 4);
#pragma unroll
        for (int i = 0; i < PW_ITERS; ++i) pw[i] = prow[i * LPR + li];
    }

    float win0 = 0.f, win1 = 0.f, win2 = 0.f;
    if (leader) {
        win0 = Win[row * 3 + 0];
        win1 = Win[row * 3 + 1];
        win2 = Win[row * 3 + 2];
    }
    __syncthreads();   // lds_x ready

    float4* const lds4 = (float4*)lds_h;

    for (int t = 0; t < TSTEPS; ++t) {
        // bias for this step (before the poll -> overlaps the wait)
        float bias = 0.f;
        if (leader)
            bias = win0 * lds_x[t * 3 + 0] + win1 * lds_x[t * 3 + 1] + win2 * lds_x[t * 3 + 2];

        if (t == 0) {
            const float4 z4 = make_float4(0.f, 0.f, 0.f, 0.f);
            for (int i = tid; i < RES / 4; i += NT) lds4[i] = z4;
            __syncthreads();
        } else {
            // ---- wait for all blocks to publish h_t: 8 lanes poll 8 group counters ----
            if (tid < NGROUP) {
                const unsigned target = (unsigned)t * (NB / NGROUP);
                while (__hip_atomic_load(&flags[tid * GSTRIDE], __ATOMIC_RELAXED,
                                         __HIP_MEMORY_SCOPE_AGENT) < target) {
                    __builtin_amdgcn_s_sleep(1);
                }
            }
            __syncthreads();
            // ---- stage h_t (fp16) into LDS as f32; conflict-free (lane stride 16B) ----
            const uint2* src = (const uint2*)(h16 + (size_t)t * (RES / 2));
#pragma unroll
            for (int k = 0; k < 4; ++k) {
                const int j = tid + k * NT;          // float4 index 0..2047
                const uint2 e = src[j];
                const float2 f0 = unpack_h2(e.x);
                const float2 f1 = unpack_h2(e.y);
                lds4[j] = make_float4(f0.x, f0.y, f1.x, f1.y);
            }
            __syncthreads();
        }

        // ---- sparse dot from register-resident W, h gathered from LDS ----
        float a0 = 0.f, a1 = 0.f, a2 = 0.f, a3 = 0.f;
#pragma unroll
        for (int i = 0; i < PW_ITERS; ++i) {
            const uint4 p = pw[i];
            a0 += __uint_as_float(p.x << 13) * lds_h[p.x >> 19];
            a1 += __uint_as_float(p.y << 13) * lds_h[p.y >> 19];
            a2 += __uint_as_float(p.z << 13) * lds_h[p.z >> 19];
            a3 += __uint_as_float(p.w << 13) * lds_h[p.w >> 19];
        }
        float acc = (a0 + a1) + (a2 + a3);
#pragma unroll
        for (int off = LPR / 2; off >= 1; off >>= 1)
            acc += __shfl_xor(acc, off, LPR);

        if (leader) lds_hnew[rlocal] = tanhf(acc + bias);
        __syncthreads();   // all gathers from lds_h done; lds_hnew ready

        // ---- publish h_{t+1}: 32 halves = one 64B line per block ----
        if (tid < 16) {
            __half2 hp = __floats2half2_rn(lds_hnew[tid * 2], lds_hnew[tid * 2 + 1]);
            const unsigned pk = *reinterpret_cast<unsigned*>(&hp);
            __hip_atomic_store(&h16[(size_t)(t + 1) * (RES / 2) + bid * 16 + tid], pk,
                               __ATOMIC_RELAXED, __HIP_MEMORY_SCOPE_AGENT);
        }
        __syncthreads();
        if (tid == 0) {
            asm volatile("s_waitcnt vmcnt(0)" ::: "memory");   // h stores at LLC
            __hip_atomic_fetch_add(&flags[grp * GSTRIDE], 1u,
                                   __ATOMIC_RELAXED, __HIP_MEMORY_SCOPE_AGENT);
        }
    }

    // ---- wait for global completion (h_{TSTEPS} published), then epilogue ----
    if (tid < NGROUP) {
        const unsigned target = (unsigned)TSTEPS * (NB / NGROUP);
        while (__hip_atomic_load(&flags[tid * GSTRIDE], __ATOMIC_RELAXED,
                                 __HIP_MEMORY_SCOPE_AGENT) < target) {
            __builtin_amdgcn_s_sleep(1);
        }
    }
    __syncthreads();

    // y_t = Wout_w @ h_{t+1} + b, two t per block, deterministic fixed-order reduce
    const float b0 = Wout_b[0], b1 = Wout_b[1], b2 = Wout_b[2];
    for (int pass = 0; pass < TSTEPS / NB; ++pass) {
        const int tout = bid * (TSTEPS / NB) + pass;
        __syncthreads();
        {
            const uint2* src = (const uint2*)(h16 + (size_t)(tout + 1) * (RES / 2));
#pragma unroll
            for (int k = 0; k < 4; ++k) {
                const int j = tid + k * NT;
                const uint2 e = src[j];
                const float2 f0 = unpack_h2(e.x);
                const float2 f1 = unpack_h2(e.y);
                lds4[j] = make_float4(f0.x, f0.y, f1.x, f1.y);
            }
        }
        __syncthreads();
        float s0 = 0.f, s1 = 0.f, s2 = 0.f;
        for (int i = tid; i < RES; i += NT) {
            const float hv = lds_h[i];
            s0 += Wout_w[i] * hv;
            s1 += Wout_w[RES + i] * hv;
            s2 += Wout_w[2 * RES + i] * hv;
        }
#pragma unroll
        for (int off = 32; off >= 1; off >>= 1) {
            s0 += __shfl_xor(s0, off, 64);
            s1 += __shfl_xor(s1, off, 64);
            s2 += __shfl_xor(s2, off, 64);
        }
        const int wv = tid >> 6;
        if ((tid & 63) == 0) { lds_red[wv][0] = s0; lds_red[wv][1] = s1; lds_red[wv][2] = s2; }
        __syncthreads();
        if (tid < 3) {
            float sum = 0.f;
            for (int w = 0; w < NT / 64; ++w) sum += lds_red[w][tid];
            out[tout * 3 + tid] = sum + (tid == 0 ? b0 : (tid == 1 ? b1 : b2));
        }
    }
}

extern "C" void kernel_launch(void* const* d_in, const int* in_sizes, int n_in,
                              void* d_out, int out_size, void* d_ws, size_t ws_size,
                              hipStream_t stream) {
    const float* x      = (const float*)d_in[0];
    const float* Win    = (const float*)d_in[1];
    const float* W      = (const float*)d_in[2];
    const float* Wout_w = (const float*)d_in[3];
    const float* Wout_b = (const float*)d_in[4];

    uint8_t* ws = (uint8_t*)d_ws;
    uint32_t* packed = (uint32_t*)(ws + WS_PACKED_OFF);
    uint32_t* h16    = (uint32_t*)(ws + WS_H16_OFF);
    unsigned* flags  = (unsigned*)(ws + WS_FLAGS_OFF);
    float*    out    = (float*)d_out;

    (void)hipMemsetAsync(flags, 0, 1024, stream);
    esn_compress<<<dim3(RES / 4), dim3(256), 0, stream>>>(W, packed);

    void* args[] = { (void*)&x, (void*)&Win, (void*)&Wout_w, (void*)&Wout_b,
                     (void*)&packed, (void*)&h16, (void*)&flags, (void*)&out };
    (void)hipLaunchCooperativeKernel((void*)esn_loop, dim3(NB), dim3(NT), args, 0u, stream);
}

// Round 6
// 2205.633 us; speedup vs baseline: 1.1235x; 1.1235x over previous
//
#include <hip/hip_runtime.h>
#include <hip/hip_fp16.h>
#include <stdint.h>

#define RES 8192
#define TSTEPS 512
#define NB 256
#define NT 512
#define ROWS_PER_BLOCK 32
#define LPR 16                           // lanes per row
#define SLOTS 72                         // 64 aligned (2 bank-rings) + 8 tail
#define PW_ITERS (SLOTS / 4)             // 18 uint4 per lane, register-resident
#define ROW_DW (SLOTS * LPR)             // 1152 dwords per packed row
#define NGROUP 8
#define GSTRIDE 16                       // dwords between group counters (64 B -> distinct lines)

// workspace layout (bytes)
#define WS_PACKED_OFF   0u
#define WS_H16_OFF      37748736u                    // 8192*1152*4
#define WS_FLAGS_OFF    (37748736u + 8404992u)       // + 513*4096*4

// entry encoding: e = (val19 << 13) | col   (col 13 bits, bank = col & 31)
// decode: val = as_float(e & 0xFFFFE000), h index = e & 8191
__global__ __launch_bounds__(256) void esn_compress(const float* __restrict__ W,
                                                    uint32_t* __restrict__ packed) {
    __shared__ uint32_t lst[4][1024];
    __shared__ uint32_t grid[4][LPR][SLOTS];
    __shared__ unsigned exc_s[4][32];
    __shared__ unsigned tbase_s[4][32];

    const int wave = threadIdx.x >> 6;
    const int lane = threadIdx.x & 63;
    const int row  = blockIdx.x * 4 + wave;
    const float* wrow = W + (size_t)row * RES;
    uint32_t* prow = packed + (size_t)row * ROW_DW;

    // ---- pass 1: compact nonzeros (rounded to 19-bit float, low-col packing) ----
    unsigned nnz = 0;
    for (int chunk = 0; chunk < RES / 64; ++chunk) {
        const int c = chunk * 64 + lane;
        const float v = wrow[c];
        const bool nz = (v != 0.0f);
        const unsigned long long m = __ballot(nz);
        if (nz) {
            unsigned pos = nnz + (unsigned)__popcll(m & ((1ull << lane) - 1ull));
            if (pos < 1024u) {
                uint32_t b = (__float_as_uint(v) + 0x1000u) & 0xFFFFE000u;
                lst[wave][pos] = b | (uint32_t)c;
            }
        }
        nnz += (unsigned)__popcll(m);
    }
    if (nnz > 1024u) nnz = 1024u;
    __syncthreads();

    // ---- prefill grid with bank-correct pads ----
    // aligned slot s<64 of lane li must read bank (rot_li + s) & 31; pad col = that bank, val = 0
    for (int d = lane; d < LPR * SLOTS; d += 64) {
        const int li = d / SLOTS;
        const int sl = d % SLOTS;
        const unsigned rot = (((unsigned)row & 1u) << 4) | (unsigned)li;
        grid[wave][li][sl] = (sl < 64) ? ((rot + (unsigned)sl) & 31u) : 0u;
    }
    __syncthreads();

    // ---- pass 2a: per-bank counts (lane b handles bank b; lst reads broadcast) ----
    if (lane < 32) {
        unsigned cb = 0;
        for (unsigned idx = 0; idx < nnz; ++idx)
            cb += ((lst[wave][idx] & 31u) == (unsigned)lane) ? 1u : 0u;
        exc_s[wave][lane] = (cb > 32u) ? (cb - 32u) : 0u;
    }
    __syncthreads();
    if (lane == 0) {
        unsigned run = 0;
        for (int b2 = 0; b2 < 32; ++b2) { tbase_s[wave][b2] = run; run += exc_s[wave][b2]; }
    }
    __syncthreads();

    // ---- pass 2b: place entries. i-th occurrence of bank b -> lane i&15, ring i>>4;
    //      overflow (i>=32) -> tail at global index tbase[b]+i-32 ----
    if (lane < 32) {
        const unsigned b = (unsigned)lane;
        const unsigned tb = tbase_s[wave][lane];
        unsigned i = 0;
        for (unsigned idx = 0; idx < nnz; ++idx) {
            const uint32_t e = lst[wave][idx];
            if ((e & 31u) == b) {
                if (i < 32u) {
                    const unsigned li = i & 15u;
                    const unsigned j  = i >> 4;
                    const unsigned rot = (((unsigned)row & 1u) << 4) | li;
                    const unsigned s = j * 32u + ((b - rot) & 31u);
                    grid[wave][li][s] = e;
                } else {
                    const unsigned q = tb + (i - 32u);
                    if (q < 128u) grid[wave][q & 15u][64u + (q >> 4)] = e;
                }
                ++i;
            }
        }
    }
    __syncthreads();

    // ---- write out; reader maps uint4 #i, lane li, comp c -> slot 4i+c ----
    for (int d = lane; d < ROW_DW; d += 64) {
        const int li = (d & 63) >> 2;
        const int sl = ((d >> 6) << 2) | (d & 3);
        prow[d] = grid[wave][li][sl];
    }
}

__device__ __forceinline__ float2 unpack_h2(unsigned u) {
    __half2 h = *reinterpret_cast<__half2*>(&u);
    return __half22float2(h);
}

__global__ __launch_bounds__(NT) void esn_loop(const float* __restrict__ x,
                                               const float* __restrict__ Win,
                                               const float* __restrict__ Wout_w,
                                               const float* __restrict__ Wout_b,
                                               const uint32_t* __restrict__ packed,
                                               uint32_t* __restrict__ h16,
                                               unsigned* __restrict__ flags,
                                               float* __restrict__ out) {
    __shared__ float lds_h[RES];
    __shared__ float lds_hnew[ROWS_PER_BLOCK];
    __shared__ float lds_red[NT / 64][3];
    __shared__ float lds_x[TSTEPS * 3];

    const int tid = threadIdx.x;
    const int bid = blockIdx.x;
    const int li  = tid & (LPR - 1);
    const int rlocal = tid >> 4;
    const int row = bid * ROWS_PER_BLOCK + rlocal;
    const bool leader = (li == 0);
    const int grp = bid & (NGROUP - 1);

    // cross-replay cache hygiene: invalidate stale clean lines once
    __builtin_amdgcn_fence(__ATOMIC_ACQUIRE, "agent");

    // stage x into LDS once
    for (int i = tid; i < TSTEPS * 3; i += NT) lds_x[i] = x[i];

    // W row slice into registers: 18 x uint4 = 72 VGPRs
    uint4 pw[PW_ITERS];
    {
        const uint4* prow = ((const uint4*)packed) + (size_t)row * (ROW_DW / 4);
#pragma unroll
        for (int i = 0; i < PW_ITERS; ++i) pw[i] = prow[i * LPR + li];
    }

    float win0 = 0.f, win1 = 0.f, win2 = 0.f;
    if (leader) {
        win0 = Win[row * 3 + 0];
        win1 = Win[row * 3 + 1];
        win2 = Win[row * 3 + 2];
    }
    __syncthreads();   // lds_x ready

    float4* const lds4 = (float4*)lds_h;

    for (int t = 0; t < TSTEPS; ++t) {
        // bias for this step (before the poll -> overlaps the wait)
        float bias = 0.f;
        if (leader)
            bias = win0 * lds_x[t * 3 + 0] + win1 * lds_x[t * 3 + 1] + win2 * lds_x[t * 3 + 2];

        if (t == 0) {
            const float4 z4 = make_float4(0.f, 0.f, 0.f, 0.f);
            for (int i = tid; i < RES / 4; i += NT) lds4[i] = z4;
            __syncthreads();
        } else {
            // ---- wait for all blocks to publish h_t: 8 lanes poll 8 group counters ----
            if (tid < NGROUP) {
                const unsigned target = (unsigned)t * (NB / NGROUP);
                while (__hip_atomic_load(&flags[tid * GSTRIDE], __ATOMIC_RELAXED,
                                         __HIP_MEMORY_SCOPE_AGENT) < target) {
                    __builtin_amdgcn_s_sleep(1);
                }
            }
            __syncthreads();
            // ---- stage h_t (fp16) into LDS as f32; conflict-free (lane stride 16B) ----
            const uint2* src = (const uint2*)(h16 + (size_t)t * (RES / 2));
#pragma unroll
            for (int k = 0; k < 4; ++k) {
                const int j = tid + k * NT;          // float4 index 0..2047
                const uint2 e = src[j];
                const float2 f0 = unpack_h2(e.x);
                const float2 f1 = unpack_h2(e.y);
                lds4[j] = make_float4(f0.x, f0.y, f1.x, f1.y);
            }
            __syncthreads();
        }

        // ---- sparse dot: per-position bank-exact schedule -> conflict-free gathers ----
        float a0 = 0.f, a1 = 0.f, a2 = 0.f, a3 = 0.f;
#pragma unroll
        for (int i = 0; i < PW_ITERS; ++i) {
            const uint4 p = pw[i];
            a0 += __uint_as_float(p.x & 0xFFFFE000u) * lds_h[p.x & 8191u];
            a1 += __uint_as_float(p.y & 0xFFFFE000u) * lds_h[p.y & 8191u];
            a2 += __uint_as_float(p.z & 0xFFFFE000u) * lds_h[p.z & 8191u];
            a3 += __uint_as_float(p.w & 0xFFFFE000u) * lds_h[p.w & 8191u];
        }
        float acc = (a0 + a1) + (a2 + a3);
#pragma unroll
        for (int off = LPR / 2; off >= 1; off >>= 1)
            acc += __shfl_xor(acc, off, LPR);

        if (leader) lds_hnew[rlocal] = tanhf(acc + bias);
        __syncthreads();   // all gathers from lds_h done; lds_hnew ready

        // ---- publish h_{t+1}: 32 halves = one 64B line per block ----
        if (tid < 16) {
            __half2 hp = __floats2half2_rn(lds_hnew[tid * 2], lds_hnew[tid * 2 + 1]);
            const unsigned pk = *reinterpret_cast<unsigned*>(&hp);
            __hip_atomic_store(&h16[(size_t)(t + 1) * (RES / 2) + bid * 16 + tid], pk,
                               __ATOMIC_RELAXED, __HIP_MEMORY_SCOPE_AGENT);
        }
        __syncthreads();
        if (tid == 0) {
            asm volatile("s_waitcnt vmcnt(0)" ::: "memory");   // h stores at LLC
            __hip_atomic_fetch_add(&flags[grp * GSTRIDE], 1u,
                                   __ATOMIC_RELAXED, __HIP_MEMORY_SCOPE_AGENT);
        }
    }

    // ---- wait for global completion (h_{TSTEPS} published), then epilogue ----
    if (tid < NGROUP) {
        const unsigned target = (unsigned)TSTEPS * (NB / NGROUP);
        while (__hip_atomic_load(&flags[tid * GSTRIDE], __ATOMIC_RELAXED,
                                 __HIP_MEMORY_SCOPE_AGENT) < target) {
            __builtin_amdgcn_s_sleep(1);
        }
    }
    __syncthreads();

    // y_t = Wout_w @ h_{t+1} + b, two t per block, deterministic fixed-order reduce
    const float b0 = Wout_b[0], b1 = Wout_b[1], b2 = Wout_b[2];
    for (int pass = 0; pass < TSTEPS / NB; ++pass) {
        const int tout = bid * (TSTEPS / NB) + pass;
        __syncthreads();
        {
            const uint2* src = (const uint2*)(h16 + (size_t)(tout + 1) * (RES / 2));
#pragma unroll
            for (int k = 0; k < 4; ++k) {
                const int j = tid + k * NT;
                const uint2 e = src[j];
                const float2 f0 = unpack_h2(e.x);
                const float2 f1 = unpack_h2(e.y);
                lds4[j] = make_float4(f0.x, f0.y, f1.x, f1.y);
            }
        }
        __syncthreads();
        float s0 = 0.f, s1 = 0.f, s2 = 0.f;
        for (int i = tid; i < RES; i += NT) {
            const float hv = lds_h[i];
            s0 += Wout_w[i] * hv;
            s1 += Wout_w[RES + i] * hv;
            s2 += Wout_w[2 * RES + i] * hv;
        }
#pragma unroll
        for (int off = 32; off >= 1; off >>= 1) {
            s0 += __shfl_xor(s0, off, 64);
            s1 += __shfl_xor(s1, off, 64);
            s2 += __shfl_xor(s2, off, 64);
        }
        const int wv = tid >> 6;
        if ((tid & 63) == 0) { lds_red[wv][0] = s0; lds_red[wv][1] = s1; lds_red[wv][2] = s2; }
        __syncthreads();
        if (tid < 3) {
            float sum = 0.f;
            for (int w = 0; w < NT / 64; ++w) sum += lds_red[w][tid];
            out[tout * 3 + tid] = sum + (tid == 0 ? b0 : (tid == 1 ? b1 : b2));
        }
    }
}

extern "C" void kernel_launch(void* const* d_in, const int* in_sizes, int n_in,
                              void* d_out, int out_size, void* d_ws, size_t ws_size,
                              hipStream_t stream) {
    const float* x      = (const float*)d_in[0];
    const float* Win    = (const float*)d_in[1];
    const float* W      = (const float*)d_in[2];
    const float* Wout_w = (const float*)d_in[3];
    const float* Wout_b = (const float*)d_in[4];

    uint8_t* ws = (uint8_t*)d_ws;
    uint32_t* packed = (uint32_t*)(ws + WS_PACKED_OFF);
    uint32_t* h16    = (uint32_t*)(ws + WS_H16_OFF);
    unsigned* flags  = (unsigned*)(ws + WS_FLAGS_OFF);
    float*    out    = (float*)d_out;

    (void)hipMemsetAsync(flags, 0, 1024, stream);
    esn_compress<<<dim3(RES / 4), dim3(256), 0, stream>>>(W, packed);

    void* args[] = { (void*)&x, (void*)&Win, (void*)&Wout_w, (void*)&Wout_b,
                     (void*)&packed, (void*)&h16, (void*)&flags, (void*)&out };
    (void)hipLaunchCooperativeKernel((void*)esn_loop, dim3(NB), dim3(NT), args, 0u, stream);
}